// Round 20
// baseline (248.670 us; speedup 1.0000x reference)
//
#include <hip/hip_runtime.h>
#include <hip/hip_bf16.h>
#include <cstdint>
#include <cstddef>

#define DEVINL __device__ __forceinline__

typedef __attribute__((ext_vector_type(4))) float   f32x4;
typedef __bf16 bf16x8 __attribute__((ext_vector_type(8)));
typedef __attribute__((ext_vector_type(4))) short   short4v;
typedef __attribute__((ext_vector_type(4))) float   float4v;

static constexpr int DIM = 1024;
static constexpr int NTOK = 4096;

// ---------- scalar helpers ----------
DEVINL unsigned short f2bf(float f) {
  unsigned u = __float_as_uint(f);
  u += 0x7FFF + ((u >> 16) & 1);
  return (unsigned short)(u >> 16);
}
DEVINL float bf2f(unsigned short s) {
  return __uint_as_float(((unsigned)s) << 16);
}

DEVINL void gll16(const void* g, void* l) {
  __builtin_amdgcn_global_load_lds(
      (const __attribute__((address_space(1))) void*)g,
      (__attribute__((address_space(3))) void*)l, 16, 0, 0);
}

// ---------- T1: bijective XCD chunk swizzle (nwg % 8 == 0 for all grids) ----------
struct B3 { int bx, by, bz; };
DEVINL B3 xcd_remap(int GX, int GY, int GZ) {
  const int flat = blockIdx.x + GX * (blockIdx.y + GY * blockIdx.z);
  const int nwg  = GX * GY * GZ;
  const int chunk = nwg >> 3;
  const int vbid = (flat & 7) * chunk + (flat >> 3);
  B3 r;
  r.bx = vbid % GX;
  r.by = (vbid / GX) % GY;
  r.bz = vbid / (GX * GY);
  return r;
}

// =====================================================================
// CORE A v3 (round 20): 256x256xK, 8 waves, SINGLE-WAIT schedule.
// vs v2 (r8/r15/r19-benched): the two VMW4s per tile drained loads
// issued only ~half a tile earlier -> each half-tile ate the ~3300-cyc
// load RTT -> 7800 cyc/tile (8.4 B/cyc, the 256^2 plateau). v3 issues
// the ENTIRE next tile's 8 gll16 at the top of each tile and waits ONCE
// (vmcnt(0)) at the bottom: the tile's ~2600 cyc of MFMA hides most of
// the RTT (r9/r12-proven mechanism).
// Ledger (1 barrier + 1 vmcnt per tile):
// - landing: each wave's own vmcnt(0) at tile end drains its T+1 stages;
//   barrier syncs all waves -> buf other fully landed before T+1 reads.
// - WAR: stage at T+1 targets buf cur(T); reads of cur(T) were consumed
//   by MFMAs before each wave reached tile-T's end barrier. Safe.
// Intra-tile: all ds_reads hit cur, stages hit other -> no intra-tile
// syncs; quadrant order and register layout identical to v2.
// T2 swizzle unchanged (0 conflicts r3-r19).
// =====================================================================
DEVINL void core256v3(const unsigned short* __restrict__ A, int lda,
                      const unsigned short* __restrict__ B, int ldb,
                      int K, int brow, int bcol, f32x4 acc[8][4])
{
  __shared__ unsigned short lds[65536];   // 128 KB: buf b at b*32768 (A), +16384 (B)
  const int t = threadIdx.x;
  const int w = t >> 6, l = t & 63;
  const int wr = w >> 2, wc = w & 3;
  const int srow = l >> 3;
  const int scol = ((l & 7) ^ srow) << 3;                    // inverse-swizzled source col
  const int l15 = l & 15;
  const int cs0 = (((l >> 4) << 3)        ^ ((l & 7) << 3)); // swizzled read col, ks=0
  const int cs1 = ((32 + ((l >> 4) << 3)) ^ ((l & 7) << 3)); // ks=1

  const unsigned short* aL = A + (size_t)(brow * 256 + srow) * lda + scol;
  const unsigned short* bL = B + (size_t)(bcol * 256 + srow) * ldb + scol;

#pragma unroll
  for (int m = 0; m < 8; ++m)
#pragma unroll
    for (int n = 0; n < 4; ++n) {
      f32x4 z = {0.f, 0.f, 0.f, 0.f};
      acc[m][n] = z;
    }

#define STA_(Sbase, h, r, kt)                                                  \
  gll16(aL + (size_t)((r)*128 + (h)*64 + (w << 3)) * lda + (size_t)(kt)*64,    \
        lds + (Sbase) + ((r)*128 + (h)*64 + (w << 3)) * 64)
#define STB_(Sbase, h, r, kt)                                                  \
  { const int g16_ = w + (r)*8;                                                \
    const int r0_ = (g16_ >> 2)*64 + (h)*32 + (g16_ & 3)*8;                    \
    gll16(bL + (size_t)r0_ * ldb + (size_t)(kt)*64, lds + (Sbase) + r0_ * 64); }
#define STAGE8(base, kt)                                                       \
  STA_((base), 0, 0, kt); STA_((base), 0, 1, kt);                              \
  STB_((base) + 16384, 0, 0, kt); STB_((base) + 16384, 0, 1, kt);              \
  STA_((base), 1, 0, kt); STA_((base), 1, 1, kt);                              \
  STB_((base) + 16384, 1, 0, kt); STB_((base) + 16384, 1, 1, kt);
#define LDA_(Abase, mh)                                                        \
  _Pragma("unroll")                                                            \
  for (int m4 = 0; m4 < 4; ++m4) {                                             \
    const unsigned short* p_ = lds + (Abase) + (wr*128 + (mh)*64 + m4*16 + l15)*64; \
    af[m4][0] = *(const bf16x8*)(p_ + cs0);                                    \
    af[m4][1] = *(const bf16x8*)(p_ + cs1);                                    \
  }
#define LDB_(Bbase, nh)                                                        \
  _Pragma("unroll")                                                            \
  for (int n2 = 0; n2 < 2; ++n2) {                                             \
    const unsigned short* p_ = lds + (Bbase) + (wc*64 + (nh)*32 + n2*16 + l15)*64;  \
    bfr[n2][0] = *(const bf16x8*)(p_ + cs0);                                   \
    bfr[n2][1] = *(const bf16x8*)(p_ + cs1);                                   \
  }
#define MF_(mh, nh)                                                            \
  __builtin_amdgcn_s_setprio(1);                                               \
  _Pragma("unroll")                                                            \
  for (int m4 = 0; m4 < 4; ++m4)                                               \
  _Pragma("unroll")                                                            \
  for (int n2 = 0; n2 < 2; ++n2) {                                             \
    f32x4 c_ = acc[(mh)*4 + m4][(nh)*2 + n2];                                  \
    c_ = __builtin_amdgcn_mfma_f32_16x16x32_bf16(af[m4][0], bfr[n2][0], c_, 0,0,0); \
    c_ = __builtin_amdgcn_mfma_f32_16x16x32_bf16(af[m4][1], bfr[n2][1], c_, 0,0,0); \
    acc[(mh)*4 + m4][(nh)*2 + n2] = c_;                                        \
  }                                                                            \
  __builtin_amdgcn_s_setprio(0);
#define VMW0() asm volatile("s_waitcnt vmcnt(0)" ::: "memory")
#define BARR() do { asm volatile("" ::: "memory");                             \
                    __builtin_amdgcn_s_barrier();                              \
                    asm volatile("" ::: "memory"); } while (0)

  // prologue: tile 0 into buf 0
  STAGE8(0, 0);
  VMW0(); BARR();

  bf16x8 af[4][2], bfr[2][2];
  const int NT = K >> 6;
  for (int kt = 0; kt < NT; ++kt) {
    const int cur = (kt & 1) * 32768;
    const int oth = cur ^ 32768;

    // issue the WHOLE next tile up front — its RTT hides under this
    // tile's ds_read + 64 MFMA.
    if (kt + 1 < NT) { STAGE8(oth, kt + 1); }

    // quadrants (all reads from cur; no intra-tile sync needed)
    LDA_(cur, 0); LDB_(cur + 16384, 0);
    MF_(0, 0);
    LDA_(cur, 1);
    MF_(1, 0);
    LDB_(cur + 16384, 1);
    MF_(1, 1);
    LDA_(cur, 0);
    MF_(0, 1);

    // single drain + barrier per tile
    VMW0(); BARR();
  }
#undef STA_
#undef STB_
#undef STAGE8
#undef LDA_
#undef LDB_
#undef MF_
#undef VMW0
#undef BARR
}

// =====================================================================
// CORE B (r12-benched; r15/r19 wall-clock-pinned best for pv):
// 256x128xK, BK=32, 8 waves (4x2), 6-buffer LDS ring (144 KB), DEPTH-4
// prefetch, counted vmcnt taper 12/9/6/3/0, stage-before-wait.
// =====================================================================
DEVINL void core256x128(const unsigned short* __restrict__ A, int lda,
                        const unsigned short* __restrict__ B, int ldb,
                        int K, int brow, int bcol, f32x4 acc[4][4])
{
  __shared__ unsigned short lds[73728];   // 144 KB = 6 x 12288 ushorts
  const int t = threadIdx.x;              // 0..511
  const int w = t >> 6, l = t & 63;
  const int wr = w >> 1, wc = w & 1;      // wave grid 4x2
  const int l15 = l & 15;
  const int scol = ((l & 3) ^ ((l >> 3) & 3)) << 3;        // staging source col
  const int cs   = (((l >> 4) ^ ((l15 >> 1) & 3)) << 3);   // read col

  const unsigned short* aL = A + (size_t)(brow * 256 + w * 16 + (l >> 2)) * lda + scol;
  const unsigned short* bL = B + (size_t)(bcol * 128 + w * 16 + (l >> 2)) * ldb + scol;

#pragma unroll
  for (int m = 0; m < 4; ++m)
#pragma unroll
    for (int n = 0; n < 4; ++n) {
      f32x4 z = {0.f, 0.f, 0.f, 0.f};
      acc[m][n] = z;
    }

#define STAGE(buf, kt)                                                         \
  {                                                                            \
    gll16(aL + (size_t)(kt) * 32,                                              \
          lds + (buf) * 12288 + w * 512);                                      \
    gll16(aL + (size_t)128 * lda + (size_t)(kt) * 32,                          \
          lds + (buf) * 12288 + 4096 + w * 512);                               \
    gll16(bL + (size_t)(kt) * 32,                                              \
          lds + (buf) * 12288 + 8192 + w * 512);                               \
  }

  const int NT = K >> 5;

  // prologue: stage tiles 0..3 into bufs 0..3 (12 loads in flight)
  STAGE(0, 0); STAGE(1, 1); STAGE(2, 2); STAGE(3, 3);

  bf16x8 af[4], bfv[4];
  int cur = 0;
  for (int kt = 0; kt < NT; ++kt) {
    int st = cur + 4; if (st >= 6) st -= 6;
    if (kt + 4 < NT) STAGE(st, kt + 4);

    const int rem = NT - 1 - kt;
    if (rem >= 4)      asm volatile("s_waitcnt vmcnt(12)" ::: "memory");
    else if (rem == 3) asm volatile("s_waitcnt vmcnt(9)"  ::: "memory");
    else if (rem == 2) asm volatile("s_waitcnt vmcnt(6)"  ::: "memory");
    else if (rem == 1) asm volatile("s_waitcnt vmcnt(3)"  ::: "memory");
    else               asm volatile("s_waitcnt vmcnt(0)"  ::: "memory");
    asm volatile("" ::: "memory");
    __builtin_amdgcn_s_barrier();
    asm volatile("" ::: "memory");

    const unsigned short* base = lds + cur * 12288;
#pragma unroll
    for (int m = 0; m < 4; ++m)
      af[m] = *(const bf16x8*)(base + (wr * 64 + m * 16 + l15) * 32 + cs);
#pragma unroll
    for (int n = 0; n < 4; ++n)
      bfv[n] = *(const bf16x8*)(base + 8192 + (wc * 64 + n * 16 + l15) * 32 + cs);

    __builtin_amdgcn_s_setprio(1);
#pragma unroll
    for (int m = 0; m < 4; ++m)
#pragma unroll
      for (int n = 0; n < 4; ++n)
        acc[m][n] = __builtin_amdgcn_mfma_f32_16x16x32_bf16(af[m], bfv[n], acc[m][n], 0, 0, 0);
    __builtin_amdgcn_s_setprio(0);

    cur = (cur + 1 == 6) ? 0 : cur + 1;
  }
#undef STAGE
}

// ---------- scores (CORE A v3): S = bf16( (A B^T) * scale ), [4096 x 4096] ----------
__global__ __launch_bounds__(512, 1)
void gemm256_scores(const unsigned short* __restrict__ A,
                    const unsigned short* __restrict__ B,
                    unsigned short* __restrict__ S, float scale)
{
  const B3 b = xcd_remap(16, 16, 1);
  f32x4 acc[8][4];
  core256v3(A, DIM, B, DIM, DIM, b.by, b.bx, acc);

  const int t = threadIdx.x, w = t >> 6, l = t & 63;
  const int wr = w >> 2, wc = w & 3;
  const int r4 = (l >> 4) * 4, c = l & 15;
  const int row0 = b.by * 256 + wr * 128;
  const int col0 = b.bx * 256 + wc * 64;
#pragma unroll
  for (int mf = 0; mf < 8; ++mf)
#pragma unroll
    for (int nf = 0; nf < 4; ++nf)
#pragma unroll
      for (int i = 0; i < 4; ++i)
        S[(size_t)(row0 + mf*16 + r4 + i) * NTOK + col0 + nf*16 + c] =
            f2bf(acc[mf][nf][i] * scale);
}

// ---------- merged QKV (CORE A v3): grid.z = 6; v outputs transposed ----------
__global__ __launch_bounds__(512, 1)
void qkv256(const unsigned short* __restrict__ x1, const unsigned short* __restrict__ x2,
            const unsigned short* __restrict__ W6,
            const float* bq1, const float* bk1, const float* bv1,
            const float* bq2, const float* bk2, const float* bv2,
            unsigned short* q1, unsigned short* k1, unsigned short* v1T,
            unsigned short* q2, unsigned short* k2, unsigned short* v2T)
{
  const B3 b = xcd_remap(4, 16, 6);
  const int g = b.bz;
  const unsigned short* A = (g < 3) ? x1 : x2;
  const unsigned short* W = W6 + (size_t)g * (DIM * DIM);
  const float* bias = (g == 0) ? bq1 : (g == 1) ? bk1 : (g == 2) ? bv1
                    : (g == 3) ? bq2 : (g == 4) ? bk2 : bv2;
  unsigned short* out = (g == 0) ? q1 : (g == 1) ? k1 : (g == 2) ? v1T
                      : (g == 3) ? q2 : (g == 4) ? k2 : v2T;
  const bool vT = (g == 2 || g == 5);

  f32x4 acc[8][4];
  core256v3(A, DIM, W, DIM, DIM, b.by, b.bx, acc);

  const int t = threadIdx.x, w = t >> 6, l = t & 63;
  const int wr = w >> 2, wc = w & 3;
  const int r4 = (l >> 4) * 4, c = l & 15;
  const int row0 = b.by * 256 + wr * 128;
  const int col0 = b.bx * 256 + wc * 64;

  float bias_v[4];
#pragma unroll
  for (int nf = 0; nf < 4; ++nf) bias_v[nf] = bias[col0 + nf*16 + c];

  if (!vT) {
#pragma unroll
    for (int mf = 0; mf < 8; ++mf)
#pragma unroll
      for (int nf = 0; nf < 4; ++nf)
#pragma unroll
        for (int i = 0; i < 4; ++i)
          out[(size_t)(row0 + mf*16 + r4 + i) * DIM + col0 + nf*16 + c] =
              f2bf(acc[mf][nf][i] + bias_v[nf]);
  } else {
#pragma unroll
    for (int mf = 0; mf < 8; ++mf)
#pragma unroll
      for (int nf = 0; nf < 4; ++nf) {
        short4v pk;
#pragma unroll
        for (int i = 0; i < 4; ++i) pk[i] = (short)f2bf(acc[mf][nf][i] + bias_v[nf]);
        *(short4v*)(out + (size_t)(col0 + nf*16 + c) * NTOK + row0 + mf*16 + r4) = pk;
      }
  }
}

// ---------- fused PV (CORE B, NO split-K): C[4096 x 2048] ----------
__global__ __launch_bounds__(512, 2)
void pv_gemm(const unsigned short* __restrict__ S1,
             const unsigned short* __restrict__ S2,
             const unsigned short* __restrict__ vTcat,
             float* __restrict__ out)
{
  const B3 b = xcd_remap(16, 16, 1);
  const int bx = b.bx, by = b.by;
  const unsigned short* A = (bx < 8) ? S1 : S2;

  f32x4 acc[4][4];
  core256x128(A, NTOK, vTcat, NTOK, NTOK, by, bx, acc);

  const int t = threadIdx.x, w = t >> 6, l = t & 63;
  const int wr = w >> 1, wc = w & 1;
  const int rr = (l >> 4) * 4, cc = l & 15;
#pragma unroll
  for (int m = 0; m < 4; ++m) {
    const int row0 = by * 256 + wr * 64 + m * 16 + rr;
#pragma unroll
    for (int n = 0; n < 4; ++n) {
      const int cg = bx * 128 + wc * 64 + n * 16 + cc;
      float* dstBase = (cg < 1024) ? (out + cg) : (out + 4194304 + (cg - 1024));
#pragma unroll
      for (int i = 0; i < 4; ++i)
        dstBase[(size_t)(row0 + i) * 1024] = acc[m][n][i];
    }
  }
}

// ---------- fused row softmax over contiguous S1||S2 (8192 rows) ----------
__global__ __launch_bounds__(256)
void softmax_inplace(unsigned short* __restrict__ S)
{
  const int row = blockIdx.x;
  unsigned short* r = S + (size_t)row * NTOK;
  const int t = threadIdx.x, wave = t >> 6, lane = t & 63;
  __shared__ float red[4];

  bf16x8 d0 = *(const bf16x8*)(r + t * 8);
  bf16x8 d1 = *(const bf16x8*)(r + 2048 + t * 8);
  float v[16];
  {
    const unsigned short* p0 = (const unsigned short*)&d0;
    const unsigned short* p1 = (const unsigned short*)&d1;
#pragma unroll
    for (int j = 0; j < 8; ++j) { v[j] = bf2f(p0[j]); v[8 + j] = bf2f(p1[j]); }
  }
  float mx = v[0];
#pragma unroll
  for (int j = 1; j < 16; ++j) mx = fmaxf(mx, v[j]);
#pragma unroll
  for (int o = 32; o > 0; o >>= 1) mx = fmaxf(mx, __shfl_xor(mx, o));
  if (lane == 0) red[wave] = mx;
  __syncthreads();
  mx = fmaxf(fmaxf(red[0], red[1]), fmaxf(red[2], red[3]));

  float s = 0.f;
#pragma unroll
  for (int j = 0; j < 16; ++j) { v[j] = __expf(v[j] - mx); s += v[j]; }
#pragma unroll
  for (int o = 32; o > 0; o >>= 1) s += __shfl_xor(s, o);
  __syncthreads();
  if (lane == 0) red[wave] = s;
  __syncthreads();
  s = red[0] + red[1] + red[2] + red[3];
  const float inv = 1.0f / s;

  unsigned short o0[8], o1[8];
#pragma unroll
  for (int j = 0; j < 8; ++j) { o0[j] = f2bf(v[j] * inv); o1[j] = f2bf(v[8 + j] * inv); }
  *(bf16x8*)(r + t * 8)        = *(const bf16x8*)o0;
  *(bf16x8*)(r + 2048 + t * 8) = *(const bf16x8*)o1;
}

// ---------- fp32 -> bf16 converters ----------
__global__ __launch_bounds__(256)
void cvt2(const float* __restrict__ a, const float* __restrict__ b,
          unsigned short* __restrict__ oa, unsigned short* __restrict__ ob)
{
  const float* in = blockIdx.y ? b : a;
  unsigned short* out = blockIdx.y ? ob : oa;
  const size_t i = ((size_t)blockIdx.x * 256 + threadIdx.x) * 4;
  float4v x = *(const float4v*)(in + i);
  short4v o;
#pragma unroll
  for (int j = 0; j < 4; ++j) o[j] = (short)f2bf(x[j]);
  *(short4v*)(out + i) = o;
}

__global__ __launch_bounds__(256)
void cvt_w(const float* w0, const float* w1, const float* w2,
           const float* w3, const float* w4, const float* w5,
           unsigned short* __restrict__ W6)
{
  const float* srcs[6] = {w0, w1, w2, w3, w4, w5};
  const float* in = srcs[blockIdx.y];
  unsigned short* out = W6 + (size_t)blockIdx.y * (DIM * DIM);
  const size_t i = ((size_t)blockIdx.x * 256 + threadIdx.x) * 4;
  float4v x = *(const float4v*)(in + i);
  short4v o;
#pragma unroll
  for (int j = 0; j < 4; ++j) o[j] = (short)f2bf(x[j]);
  *(short4v*)(out + i) = o;
}

// ---------- host launcher ----------
extern "C" void kernel_launch(void* const* d_in, const int* in_sizes, int n_in,
                              void* d_out, int out_size, void* d_ws, size_t ws_size,
                              hipStream_t stream)
{
  const float* x1  = (const float*)d_in[0];
  const float* x2  = (const float*)d_in[1];
  const float* Wq1 = (const float*)d_in[2];  const float* bq1 = (const float*)d_in[3];
  const float* Wk1 = (const float*)d_in[4];  const float* bk1 = (const float*)d_in[5];
  const float* Wv1 = (const float*)d_in[6];  const float* bv1 = (const float*)d_in[7];
  const float* Wq2 = (const float*)d_in[8];  const float* bq2 = (const float*)d_in[9];
  const float* Wk2 = (const float*)d_in[10]; const float* bk2 = (const float*)d_in[11];
  const float* Wv2 = (const float*)d_in[12]; const float* bv2 = (const float*)d_in[13];
  float* out = (float*)d_out;

  // ws layout (ushort units):
  //  [0,16M):    x1b(4M) x2b(4M) W6(6M) pad -> later S1 [4096x4096]
  //  [16M,32M):  S2   (contiguous with S1 -> fused softmax over 8192 rows)
  //  [32M,48M):  q1 k1 q2 k2 (4M each)
  //  [48M,56M):  v1T v2T (vTcat, [2048 x 4096])
  unsigned short* ws  = (unsigned short*)d_ws;
  const size_t NTD = (size_t)NTOK * DIM;           // 4M elems
  const size_t SM  = (size_t)NTOK * NTOK;          // 16M elems
  unsigned short* x1b = ws;
  unsigned short* x2b = x1b + NTD;
  unsigned short* W6  = x2b + NTD;
  unsigned short* S1  = ws;
  unsigned short* S2  = ws + SM;
  unsigned short* q1  = ws + 2 * SM;
  unsigned short* k1  = q1 + NTD;
  unsigned short* q2  = k1 + NTD;
  unsigned short* k2  = q2 + NTD;
  unsigned short* vT  = k2 + NTD;                  // v1T followed by v2T
  unsigned short* v1T = vT;
  unsigned short* v2T = vT + NTD;

  const dim3 blk(256);
  cvt2 <<<dim3(NTD / 1024, 2), blk, 0, stream>>>(x1, x2, x1b, x2b);
  cvt_w<<<dim3((DIM * DIM) / 1024, 6), blk, 0, stream>>>(Wq1, Wk1, Wv1, Wq2, Wk2, Wv2, W6);

  qkv256<<<dim3(4, 16, 6), dim3(512), 0, stream>>>(
      x1b, x2b, W6, bq1, bk1, bv1, bq2, bk2, bv2, q1, k1, v1T, q2, k2, v2T);

  const float scale = 0.03125f;  // 1/sqrt(1024)

  // two separate score launches (r15-verified remap / L2 behavior),
  // then ONE fused softmax over the contiguous S1||S2 region
  gemm256_scores<<<dim3(16, 16), dim3(512), 0, stream>>>(q2, k1, S1, scale);
  gemm256_scores<<<dim3(16, 16), dim3(512), 0, stream>>>(q1, k2, S2, scale);
  softmax_inplace<<<dim3(2 * NTOK), blk, 0, stream>>>(S1);

  // fused PV over [v1T; v2T], full K (no split, no partial add)
  pv_gemm<<<dim3(16, 16), dim3(512), 0, stream>>>(S1, S2, vT, out);
}

// Round 21
// 245.058 us; speedup vs baseline: 1.0147x; 1.0147x over previous
//
#include <hip/hip_runtime.h>
#include <hip/hip_bf16.h>
#include <cstdint>
#include <cstddef>

#define DEVINL __device__ __forceinline__

typedef __attribute__((ext_vector_type(4))) float   f32x4;
typedef __bf16 bf16x8 __attribute__((ext_vector_type(8)));
typedef __attribute__((ext_vector_type(4))) short   short4v;
typedef __attribute__((ext_vector_type(4))) float   float4v;

static constexpr int DIM = 1024;
static constexpr int NTOK = 4096;

// ---------- scalar helpers ----------
DEVINL unsigned short f2bf(float f) {
  unsigned u = __float_as_uint(f);
  u += 0x7FFF + ((u >> 16) & 1);
  return (unsigned short)(u >> 16);
}
DEVINL float bf2f(unsigned short s) {
  return __uint_as_float(((unsigned)s) << 16);
}

DEVINL void gll16(const void* g, void* l) {
  __builtin_amdgcn_global_load_lds(
      (const __attribute__((address_space(1))) void*)g,
      (__attribute__((address_space(3))) void*)l, 16, 0, 0);
}

// ---------- T1: bijective XCD chunk swizzle (nwg % 8 == 0 for all grids) ----------
struct B3 { int bx, by, bz; };
DEVINL B3 xcd_remap(int GX, int GY, int GZ) {
  const int flat = blockIdx.x + GX * (blockIdx.y + GY * blockIdx.z);
  const int nwg  = GX * GY * GZ;
  const int chunk = nwg >> 3;
  const int vbid = (flat & 7) * chunk + (flat >> 3);
  B3 r;
  r.bx = vbid % GX;
  r.by = (vbid / GX) % GY;
  r.bz = vbid / (GX * GY);
  return r;
}

// =====================================================================
// CORE A (r8/r15/r19-benched; wall-clock-pinned best for qkv + scores):
// 256x256xK, 8 waves, v2 schedule — 2 barriers + 2 counted vmcnt per
// K-tile, p2/p3 free-run. Single bfr[2][2] B-set.
// =====================================================================
DEVINL void core256v2(const unsigned short* __restrict__ A, int lda,
                      const unsigned short* __restrict__ B, int ldb,
                      int K, int brow, int bcol, f32x4 acc[8][4])
{
  __shared__ unsigned short lds[65536];   // 128 KB
  const int t = threadIdx.x;
  const int w = t >> 6, l = t & 63;
  const int wr = w >> 2, wc = w & 3;
  const int srow = l >> 3;
  const int scol = ((l & 7) ^ srow) << 3;                    // inverse-swizzled source col
  const int l15 = l & 15;
  const int cs0 = (((l >> 4) << 3)        ^ ((l & 7) << 3)); // swizzled read col, ks=0
  const int cs1 = ((32 + ((l >> 4) << 3)) ^ ((l & 7) << 3)); // ks=1

  const unsigned short* aL = A + (size_t)(brow * 256 + srow) * lda + scol;
  const unsigned short* bL = B + (size_t)(bcol * 256 + srow) * ldb + scol;

#pragma unroll
  for (int m = 0; m < 8; ++m)
#pragma unroll
    for (int n = 0; n < 4; ++n) {
      f32x4 z = {0.f, 0.f, 0.f, 0.f};
      acc[m][n] = z;
    }

#define STA_(Sbase, h, r, kt)                                                  \
  gll16(aL + (size_t)((r)*128 + (h)*64 + (w << 3)) * lda + (size_t)(kt)*64,    \
        lds + (Sbase) + ((r)*128 + (h)*64 + (w << 3)) * 64)
#define STB_(Sbase, h, r, kt)                                                  \
  { const int g16_ = w + (r)*8;                                                \
    const int r0_ = (g16_ >> 2)*64 + (h)*32 + (g16_ & 3)*8;                    \
    gll16(bL + (size_t)r0_ * ldb + (size_t)(kt)*64, lds + (Sbase) + r0_ * 64); }
#define LDA_(Abase, mh)                                                        \
  _Pragma("unroll")                                                            \
  for (int m4 = 0; m4 < 4; ++m4) {                                             \
    const unsigned short* p_ = lds + (Abase) + (wr*128 + (mh)*64 + m4*16 + l15)*64; \
    af[m4][0] = *(const bf16x8*)(p_ + cs0);                                    \
    af[m4][1] = *(const bf16x8*)(p_ + cs1);                                    \
  }
#define LDB_(Bbase, nh)                                                        \
  _Pragma("unroll")                                                            \
  for (int n2 = 0; n2 < 2; ++n2) {                                             \
    const unsigned short* p_ = lds + (Bbase) + (wc*64 + (nh)*32 + n2*16 + l15)*64;  \
    bfr[n2][0] = *(const bf16x8*)(p_ + cs0);                                   \
    bfr[n2][1] = *(const bf16x8*)(p_ + cs1);                                   \
  }
#define MF_(mh, nh)                                                            \
  __builtin_amdgcn_s_setprio(1);                                               \
  _Pragma("unroll")                                                            \
  for (int m4 = 0; m4 < 4; ++m4)                                               \
  _Pragma("unroll")                                                            \
  for (int n2 = 0; n2 < 2; ++n2) {                                             \
    f32x4 c_ = acc[(mh)*4 + m4][(nh)*2 + n2];                                  \
    c_ = __builtin_amdgcn_mfma_f32_16x16x32_bf16(af[m4][0], bfr[n2][0], c_, 0,0,0); \
    c_ = __builtin_amdgcn_mfma_f32_16x16x32_bf16(af[m4][1], bfr[n2][1], c_, 0,0,0); \
    acc[(mh)*4 + m4][(nh)*2 + n2] = c_;                                        \
  }                                                                            \
  __builtin_amdgcn_s_setprio(0);
#define VMW4() asm volatile("s_waitcnt vmcnt(4)" ::: "memory")
#define VMW0() asm volatile("s_waitcnt vmcnt(0)" ::: "memory")
#define BARR() do { asm volatile("" ::: "memory");                             \
                    __builtin_amdgcn_s_barrier();                              \
                    asm volatile("" ::: "memory"); } while (0)

  // prologue: tile 0, groups [A0,B0] then [A1,B1]
  STA_(0, 0, 0, 0); STA_(0, 0, 1, 0); STB_(16384, 0, 0, 0); STB_(16384, 0, 1, 0);
  STA_(0, 1, 0, 0); STA_(0, 1, 1, 0); STB_(16384, 1, 0, 0); STB_(16384, 1, 1, 0);

  bf16x8 af[4][2], bfr[2][2];
  const int NT = K >> 6;
  for (int kt = 0; kt < NT - 1; ++kt) {
    const int Ab = (kt & 1) * 32768;
    const int Bb = Ab + 16384;
    const int Sa = ((kt & 1) ^ 1) * 32768;
    const int Sb = Sa + 16384;

    // p0: quadrant (m0,n0)
    VMW4(); BARR();
    STA_(Sa, 0, 0, kt + 1); STA_(Sa, 0, 1, kt + 1);
    STB_(Sb, 0, 0, kt + 1); STB_(Sb, 0, 1, kt + 1);
    LDA_(Ab, 0); LDB_(Bb, 0);
    MF_(0, 0);

    // p1: quadrant (m1,n0) — bfr (B half 0) held
    VMW4(); BARR();
    STA_(Sa, 1, 0, kt + 1); STA_(Sa, 1, 1, kt + 1);
    STB_(Sb, 1, 0, kt + 1); STB_(Sb, 1, 1, kt + 1);
    LDA_(Ab, 1);
    MF_(1, 0);

    // p2: quadrant (m1,n1) — free-running, reload bfr with B half 1
    LDB_(Bb, 1);
    MF_(1, 1);

    // p3: quadrant (m0,n1) — free-running, bfr held
    LDA_(Ab, 0);
    MF_(0, 1);
  }

  // peeled last tile
  {
    const int kt = NT - 1;
    const int Ab = (kt & 1) * 32768;
    const int Bb = Ab + 16384;
    VMW4(); BARR();
    LDA_(Ab, 0); LDB_(Bb, 0);
    MF_(0, 0);
    VMW0(); BARR();
    LDA_(Ab, 1);
    MF_(1, 0);
    LDB_(Bb, 1);
    MF_(1, 1);
    LDA_(Ab, 0);
    MF_(0, 1);
  }
#undef STA_
#undef STB_
#undef LDA_
#undef LDB_
#undef MF_
#undef VMW4
#undef VMW0
#undef BARR
}

// =====================================================================
// CORE B (r12-benched; r15/r19 wall-clock-pinned best for pv):
// 256x128xK, BK=32, 8 waves (4x2), 6-buffer LDS ring (144 KB), DEPTH-4
// prefetch, counted vmcnt taper 12/9/6/3/0, stage-before-wait.
// =====================================================================
DEVINL void core256x128(const unsigned short* __restrict__ A, int lda,
                        const unsigned short* __restrict__ B, int ldb,
                        int K, int brow, int bcol, f32x4 acc[4][4])
{
  __shared__ unsigned short lds[73728];   // 144 KB = 6 x 12288 ushorts
  const int t = threadIdx.x;              // 0..511
  const int w = t >> 6, l = t & 63;
  const int wr = w >> 1, wc = w & 1;      // wave grid 4x2
  const int l15 = l & 15;
  const int scol = ((l & 3) ^ ((l >> 3) & 3)) << 3;        // staging source col
  const int cs   = (((l >> 4) ^ ((l15 >> 1) & 3)) << 3);   // read col

  const unsigned short* aL = A + (size_t)(brow * 256 + w * 16 + (l >> 2)) * lda + scol;
  const unsigned short* bL = B + (size_t)(bcol * 128 + w * 16 + (l >> 2)) * ldb + scol;

#pragma unroll
  for (int m = 0; m < 4; ++m)
#pragma unroll
    for (int n = 0; n < 4; ++n) {
      f32x4 z = {0.f, 0.f, 0.f, 0.f};
      acc[m][n] = z;
    }

#define STAGE(buf, kt)                                                         \
  {                                                                            \
    gll16(aL + (size_t)(kt) * 32,                                              \
          lds + (buf) * 12288 + w * 512);                                      \
    gll16(aL + (size_t)128 * lda + (size_t)(kt) * 32,                          \
          lds + (buf) * 12288 + 4096 + w * 512);                               \
    gll16(bL + (size_t)(kt) * 32,                                              \
          lds + (buf) * 12288 + 8192 + w * 512);                               \
  }

  const int NT = K >> 5;

  // prologue: stage tiles 0..3 into bufs 0..3 (12 loads in flight)
  STAGE(0, 0); STAGE(1, 1); STAGE(2, 2); STAGE(3, 3);

  bf16x8 af[4], bfv[4];
  int cur = 0;
  for (int kt = 0; kt < NT; ++kt) {
    int st = cur + 4; if (st >= 6) st -= 6;
    if (kt + 4 < NT) STAGE(st, kt + 4);

    const int rem = NT - 1 - kt;
    if (rem >= 4)      asm volatile("s_waitcnt vmcnt(12)" ::: "memory");
    else if (rem == 3) asm volatile("s_waitcnt vmcnt(9)"  ::: "memory");
    else if (rem == 2) asm volatile("s_waitcnt vmcnt(6)"  ::: "memory");
    else if (rem == 1) asm volatile("s_waitcnt vmcnt(3)"  ::: "memory");
    else               asm volatile("s_waitcnt vmcnt(0)"  ::: "memory");
    asm volatile("" ::: "memory");
    __builtin_amdgcn_s_barrier();
    asm volatile("" ::: "memory");

    const unsigned short* base = lds + cur * 12288;
#pragma unroll
    for (int m = 0; m < 4; ++m)
      af[m] = *(const bf16x8*)(base + (wr * 64 + m * 16 + l15) * 32 + cs);
#pragma unroll
    for (int n = 0; n < 4; ++n)
      bfv[n] = *(const bf16x8*)(base + 8192 + (wc * 64 + n * 16 + l15) * 32 + cs);

    __builtin_amdgcn_s_setprio(1);
#pragma unroll
    for (int m = 0; m < 4; ++m)
#pragma unroll
      for (int n = 0; n < 4; ++n)
        acc[m][n] = __builtin_amdgcn_mfma_f32_16x16x32_bf16(af[m], bfv[n], acc[m][n], 0, 0, 0);
    __builtin_amdgcn_s_setprio(0);

    cur = (cur + 1 == 6) ? 0 : cur + 1;
  }
#undef STAGE
}

// ---------- scores (CORE A): S = bf16( (A B^T) * scale ), [4096 x 4096] ----------
__global__ __launch_bounds__(512, 1)
void gemm256_scores(const unsigned short* __restrict__ A,
                    const unsigned short* __restrict__ B,
                    unsigned short* __restrict__ S, float scale)
{
  const B3 b = xcd_remap(16, 16, 1);
  f32x4 acc[8][4];
  core256v2(A, DIM, B, DIM, DIM, b.by, b.bx, acc);

  const int t = threadIdx.x, w = t >> 6, l = t & 63;
  const int wr = w >> 2, wc = w & 3;
  const int r4 = (l >> 4) * 4, c = l & 15;
  const int row0 = b.by * 256 + wr * 128;
  const int col0 = b.bx * 256 + wc * 64;
#pragma unroll
  for (int mf = 0; mf < 8; ++mf)
#pragma unroll
    for (int nf = 0; nf < 4; ++nf)
#pragma unroll
      for (int i = 0; i < 4; ++i)
        S[(size_t)(row0 + mf*16 + r4 + i) * NTOK + col0 + nf*16 + c] =
            f2bf(acc[mf][nf][i] * scale);
}

// ---------- merged QKV (CORE A): grid.z = 6; v outputs transposed ----------
__global__ __launch_bounds__(512, 1)
void qkv256(const unsigned short* __restrict__ x1, const unsigned short* __restrict__ x2,
            const unsigned short* __restrict__ W6,
            const float* bq1, const float* bk1, const float* bv1,
            const float* bq2, const float* bk2, const float* bv2,
            unsigned short* q1, unsigned short* k1, unsigned short* v1T,
            unsigned short* q2, unsigned short* k2, unsigned short* v2T)
{
  const B3 b = xcd_remap(4, 16, 6);
  const int g = b.bz;
  const unsigned short* A = (g < 3) ? x1 : x2;
  const unsigned short* W = W6 + (size_t)g * (DIM * DIM);
  const float* bias = (g == 0) ? bq1 : (g == 1) ? bk1 : (g == 2) ? bv1
                    : (g == 3) ? bq2 : (g == 4) ? bk2 : bv2;
  unsigned short* out = (g == 0) ? q1 : (g == 1) ? k1 : (g == 2) ? v1T
                      : (g == 3) ? q2 : (g == 4) ? k2 : v2T;
  const bool vT = (g == 2 || g == 5);

  f32x4 acc[8][4];
  core256v2(A, DIM, W, DIM, DIM, b.by, b.bx, acc);

  const int t = threadIdx.x, w = t >> 6, l = t & 63;
  const int wr = w >> 2, wc = w & 3;
  const int r4 = (l >> 4) * 4, c = l & 15;
  const int row0 = b.by * 256 + wr * 128;
  const int col0 = b.bx * 256 + wc * 64;

  float bias_v[4];
#pragma unroll
  for (int nf = 0; nf < 4; ++nf) bias_v[nf] = bias[col0 + nf*16 + c];

  if (!vT) {
#pragma unroll
    for (int mf = 0; mf < 8; ++mf)
#pragma unroll
      for (int nf = 0; nf < 4; ++nf)
#pragma unroll
        for (int i = 0; i < 4; ++i)
          out[(size_t)(row0 + mf*16 + r4 + i) * DIM + col0 + nf*16 + c] =
              f2bf(acc[mf][nf][i] + bias_v[nf]);
  } else {
#pragma unroll
    for (int mf = 0; mf < 8; ++mf)
#pragma unroll
      for (int nf = 0; nf < 4; ++nf) {
        short4v pk;
#pragma unroll
        for (int i = 0; i < 4; ++i) pk[i] = (short)f2bf(acc[mf][nf][i] + bias_v[nf]);
        *(short4v*)(out + (size_t)(col0 + nf*16 + c) * NTOK + row0 + mf*16 + r4) = pk;
      }
  }
}

// ---------- fused PV (CORE B, NO split-K): C[4096 x 2048] ----------
__global__ __launch_bounds__(512, 2)
void pv_gemm(const unsigned short* __restrict__ S1,
             const unsigned short* __restrict__ S2,
             const unsigned short* __restrict__ vTcat,
             float* __restrict__ out)
{
  const B3 b = xcd_remap(16, 16, 1);
  const int bx = b.bx, by = b.by;
  const unsigned short* A = (bx < 8) ? S1 : S2;

  f32x4 acc[4][4];
  core256x128(A, NTOK, vTcat, NTOK, NTOK, by, bx, acc);

  const int t = threadIdx.x, w = t >> 6, l = t & 63;
  const int wr = w >> 1, wc = w & 1;
  const int rr = (l >> 4) * 4, cc = l & 15;
#pragma unroll
  for (int m = 0; m < 4; ++m) {
    const int row0 = by * 256 + wr * 64 + m * 16 + rr;
#pragma unroll
    for (int n = 0; n < 4; ++n) {
      const int cg = bx * 128 + wc * 64 + n * 16 + cc;
      float* dstBase = (cg < 1024) ? (out + cg) : (out + 4194304 + (cg - 1024));
#pragma unroll
      for (int i = 0; i < 4; ++i)
        dstBase[(size_t)(row0 + i) * 1024] = acc[m][n][i];
    }
  }
}

// ---------- fused row softmax over contiguous S1||S2 (8192 rows) ----------
__global__ __launch_bounds__(256)
void softmax_inplace(unsigned short* __restrict__ S)
{
  const int row = blockIdx.x;
  unsigned short* r = S + (size_t)row * NTOK;
  const int t = threadIdx.x, wave = t >> 6, lane = t & 63;
  __shared__ float red[4];

  bf16x8 d0 = *(const bf16x8*)(r + t * 8);
  bf16x8 d1 = *(const bf16x8*)(r + 2048 + t * 8);
  float v[16];
  {
    const unsigned short* p0 = (const unsigned short*)&d0;
    const unsigned short* p1 = (const unsigned short*)&d1;
#pragma unroll
    for (int j = 0; j < 8; ++j) { v[j] = bf2f(p0[j]); v[8 + j] = bf2f(p1[j]); }
  }
  float mx = v[0];
#pragma unroll
  for (int j = 1; j < 16; ++j) mx = fmaxf(mx, v[j]);
#pragma unroll
  for (int o = 32; o > 0; o >>= 1) mx = fmaxf(mx, __shfl_xor(mx, o));
  if (lane == 0) red[wave] = mx;
  __syncthreads();
  mx = fmaxf(fmaxf(red[0], red[1]), fmaxf(red[2], red[3]));

  float s = 0.f;
#pragma unroll
  for (int j = 0; j < 16; ++j) { v[j] = __expf(v[j] - mx); s += v[j]; }
#pragma unroll
  for (int o = 32; o > 0; o >>= 1) s += __shfl_xor(s, o);
  __syncthreads();
  if (lane == 0) red[wave] = s;
  __syncthreads();
  s = red[0] + red[1] + red[2] + red[3];
  const float inv = 1.0f / s;

  unsigned short o0[8], o1[8];
#pragma unroll
  for (int j = 0; j < 8; ++j) { o0[j] = f2bf(v[j] * inv); o1[j] = f2bf(v[8 + j] * inv); }
  *(bf16x8*)(r + t * 8)        = *(const bf16x8*)o0;
  *(bf16x8*)(r + 2048 + t * 8) = *(const bf16x8*)o1;
}

// ---------- fp32 -> bf16 converters ----------
__global__ __launch_bounds__(256)
void cvt2(const float* __restrict__ a, const float* __restrict__ b,
          unsigned short* __restrict__ oa, unsigned short* __restrict__ ob)
{
  const float* in = blockIdx.y ? b : a;
  unsigned short* out = blockIdx.y ? ob : oa;
  const size_t i = ((size_t)blockIdx.x * 256 + threadIdx.x) * 4;
  float4v x = *(const float4v*)(in + i);
  short4v o;
#pragma unroll
  for (int j = 0; j < 4; ++j) o[j] = (short)f2bf(x[j]);
  *(short4v*)(out + i) = o;
}

__global__ __launch_bounds__(256)
void cvt_w(const float* w0, const float* w1, const float* w2,
           const float* w3, const float* w4, const float* w5,
           unsigned short* __restrict__ W6)
{
  const float* srcs[6] = {w0, w1, w2, w3, w4, w5};
  const float* in = srcs[blockIdx.y];
  unsigned short* out = W6 + (size_t)blockIdx.y * (DIM * DIM);
  const size_t i = ((size_t)blockIdx.x * 256 + threadIdx.x) * 4;
  float4v x = *(const float4v*)(in + i);
  short4v o;
#pragma unroll
  for (int j = 0; j < 4; ++j) o[j] = (short)f2bf(x[j]);
  *(short4v*)(out + i) = o;
}

// ---------- host launcher ----------
extern "C" void kernel_launch(void* const* d_in, const int* in_sizes, int n_in,
                              void* d_out, int out_size, void* d_ws, size_t ws_size,
                              hipStream_t stream)
{
  const float* x1  = (const float*)d_in[0];
  const float* x2  = (const float*)d_in[1];
  const float* Wq1 = (const float*)d_in[2];  const float* bq1 = (const float*)d_in[3];
  const float* Wk1 = (const float*)d_in[4];  const float* bk1 = (const float*)d_in[5];
  const float* Wv1 = (const float*)d_in[6];  const float* bv1 = (const float*)d_in[7];
  const float* Wq2 = (const float*)d_in[8];  const float* bq2 = (const float*)d_in[9];
  const float* Wk2 = (const float*)d_in[10]; const float* bk2 = (const float*)d_in[11];
  const float* Wv2 = (const float*)d_in[12]; const float* bv2 = (const float*)d_in[13];
  float* out = (float*)d_out;

  // ws layout (ushort units):
  //  [0,16M):    x1b(4M) x2b(4M) W6(6M) pad -> later S1 [4096x4096]
  //  [16M,32M):  S2   (contiguous with S1 -> fused softmax over 8192 rows)
  //  [32M,48M):  q1 k1 q2 k2 (4M each)
  //  [48M,56M):  v1T v2T (vTcat, [2048 x 4096])
  unsigned short* ws  = (unsigned short*)d_ws;
  const size_t NTD = (size_t)NTOK * DIM;           // 4M elems
  const size_t SM  = (size_t)NTOK * NTOK;          // 16M elems
  unsigned short* x1b = ws;
  unsigned short* x2b = x1b + NTD;
  unsigned short* W6  = x2b + NTD;
  unsigned short* S1  = ws;
  unsigned short* S2  = ws + SM;
  unsigned short* q1  = ws + 2 * SM;
  unsigned short* k1  = q1 + NTD;
  unsigned short* q2  = k1 + NTD;
  unsigned short* k2  = q2 + NTD;
  unsigned short* vT  = k2 + NTD;                  // v1T followed by v2T
  unsigned short* v1T = vT;
  unsigned short* v2T = vT + NTD;

  const dim3 blk(256);
  cvt2 <<<dim3(NTD / 1024, 2), blk, 0, stream>>>(x1, x2, x1b, x2b);
  cvt_w<<<dim3((DIM * DIM) / 1024, 6), blk, 0, stream>>>(Wq1, Wk1, Wv1, Wq2, Wk2, Wv2, W6);

  qkv256<<<dim3(4, 16, 6), dim3(512), 0, stream>>>(
      x1b, x2b, W6, bq1, bk1, bv1, bq2, bk2, bv2, q1, k1, v1T, q2, k2, v2T);

  const float scale = 0.03125f;  // 1/sqrt(1024)

  // two separate score launches (r15-verified remap / L2 behavior),
  // then ONE fused softmax over the contiguous S1||S2 region
  gemm256_scores<<<dim3(16, 16), dim3(512), 0, stream>>>(q2, k1, S1, scale);
  gemm256_scores<<<dim3(16, 16), dim3(512), 0, stream>>>(q1, k2, S2, scale);
  softmax_inplace<<<dim3(2 * NTOK), blk, 0, stream>>>(S1);

  // fused PV over [v1T; v2T], full K (no split, no partial add)
  pv_gemm<<<dim3(16, 16), dim3(512), 0, stream>>>(S1, S2, vT, out);
}

// Round 22
// 243.342 us; speedup vs baseline: 1.0219x; 1.0070x over previous
//
#include <hip/hip_runtime.h>
#include <hip/hip_bf16.h>
#include <cstdint>
#include <cstddef>

#define DEVINL __device__ __forceinline__

typedef __attribute__((ext_vector_type(4))) float   f32x4;
typedef __bf16 bf16x8 __attribute__((ext_vector_type(8)));
typedef __attribute__((ext_vector_type(4))) short   short4v;
typedef __attribute__((ext_vector_type(4))) float   float4v;

static constexpr int DIM = 1024;
static constexpr int NTOK = 4096;

// ---------- scalar helpers ----------
DEVINL unsigned short f2bf(float f) {
  unsigned u = __float_as_uint(f);
  u += 0x7FFF + ((u >> 16) & 1);
  return (unsigned short)(u >> 16);
}
DEVINL float bf2f(unsigned short s) {
  return __uint_as_float(((unsigned)s) << 16);
}

DEVINL void gll16(const void* g, void* l) {
  __builtin_amdgcn_global_load_lds(
      (const __attribute__((address_space(1))) void*)g,
      (__attribute__((address_space(3))) void*)l, 16, 0, 0);
}

// ---------- T1: bijective XCD chunk swizzle (nwg % 8 == 0 for all grids) ----------
struct B3 { int bx, by, bz; };
DEVINL B3 xcd_remap(int GX, int GY, int GZ) {
  const int flat = blockIdx.x + GX * (blockIdx.y + GY * blockIdx.z);
  const int nwg  = GX * GY * GZ;
  const int chunk = nwg >> 3;
  const int vbid = (flat & 7) * chunk + (flat >> 3);
  B3 r;
  r.bx = vbid % GX;
  r.by = (vbid / GX) % GY;
  r.bz = vbid / (GX * GY);
  return r;
}

// =====================================================================
// CORE A (r8/r15/r19/r21-benched; wall-clock-pinned best for qkv+scores):
// 256x256xK, 8 waves, v2 schedule — 2 barriers + 2 counted vmcnt per
// K-tile, p2/p3 free-run. Single bfr[2][2] B-set.
// =====================================================================
DEVINL void core256v2(const unsigned short* __restrict__ A, int lda,
                      const unsigned short* __restrict__ B, int ldb,
                      int K, int brow, int bcol, f32x4 acc[8][4])
{
  __shared__ unsigned short lds[65536];   // 128 KB
  const int t = threadIdx.x;
  const int w = t >> 6, l = t & 63;
  const int wr = w >> 2, wc = w & 3;
  const int srow = l >> 3;
  const int scol = ((l & 7) ^ srow) << 3;                    // inverse-swizzled source col
  const int l15 = l & 15;
  const int cs0 = (((l >> 4) << 3)        ^ ((l & 7) << 3)); // swizzled read col, ks=0
  const int cs1 = ((32 + ((l >> 4) << 3)) ^ ((l & 7) << 3)); // ks=1

  const unsigned short* aL = A + (size_t)(brow * 256 + srow) * lda + scol;
  const unsigned short* bL = B + (size_t)(bcol * 256 + srow) * ldb + scol;

#pragma unroll
  for (int m = 0; m < 8; ++m)
#pragma unroll
    for (int n = 0; n < 4; ++n) {
      f32x4 z = {0.f, 0.f, 0.f, 0.f};
      acc[m][n] = z;
    }

#define STA_(Sbase, h, r, kt)                                                  \
  gll16(aL + (size_t)((r)*128 + (h)*64 + (w << 3)) * lda + (size_t)(kt)*64,    \
        lds + (Sbase) + ((r)*128 + (h)*64 + (w << 3)) * 64)
#define STB_(Sbase, h, r, kt)                                                  \
  { const int g16_ = w + (r)*8;                                                \
    const int r0_ = (g16_ >> 2)*64 + (h)*32 + (g16_ & 3)*8;                    \
    gll16(bL + (size_t)r0_ * ldb + (size_t)(kt)*64, lds + (Sbase) + r0_ * 64); }
#define LDA_(Abase, mh)                                                        \
  _Pragma("unroll")                                                            \
  for (int m4 = 0; m4 < 4; ++m4) {                                             \
    const unsigned short* p_ = lds + (Abase) + (wr*128 + (mh)*64 + m4*16 + l15)*64; \
    af[m4][0] = *(const bf16x8*)(p_ + cs0);                                    \
    af[m4][1] = *(const bf16x8*)(p_ + cs1);                                    \
  }
#define LDB_(Bbase, nh)                                                        \
  _Pragma("unroll")                                                            \
  for (int n2 = 0; n2 < 2; ++n2) {                                             \
    const unsigned short* p_ = lds + (Bbase) + (wc*64 + (nh)*32 + n2*16 + l15)*64;  \
    bfr[n2][0] = *(const bf16x8*)(p_ + cs0);                                   \
    bfr[n2][1] = *(const bf16x8*)(p_ + cs1);                                   \
  }
#define MF_(mh, nh)                                                            \
  __builtin_amdgcn_s_setprio(1);                                               \
  _Pragma("unroll")                                                            \
  for (int m4 = 0; m4 < 4; ++m4)                                               \
  _Pragma("unroll")                                                            \
  for (int n2 = 0; n2 < 2; ++n2) {                                             \
    f32x4 c_ = acc[(mh)*4 + m4][(nh)*2 + n2];                                  \
    c_ = __builtin_amdgcn_mfma_f32_16x16x32_bf16(af[m4][0], bfr[n2][0], c_, 0,0,0); \
    c_ = __builtin_amdgcn_mfma_f32_16x16x32_bf16(af[m4][1], bfr[n2][1], c_, 0,0,0); \
    acc[(mh)*4 + m4][(nh)*2 + n2] = c_;                                        \
  }                                                                            \
  __builtin_amdgcn_s_setprio(0);
#define VMW4() asm volatile("s_waitcnt vmcnt(4)" ::: "memory")
#define VMW0() asm volatile("s_waitcnt vmcnt(0)" ::: "memory")
#define BARR() do { asm volatile("" ::: "memory");                             \
                    __builtin_amdgcn_s_barrier();                              \
                    asm volatile("" ::: "memory"); } while (0)

  // prologue: tile 0, groups [A0,B0] then [A1,B1]
  STA_(0, 0, 0, 0); STA_(0, 0, 1, 0); STB_(16384, 0, 0, 0); STB_(16384, 0, 1, 0);
  STA_(0, 1, 0, 0); STA_(0, 1, 1, 0); STB_(16384, 1, 0, 0); STB_(16384, 1, 1, 0);

  bf16x8 af[4][2], bfr[2][2];
  const int NT = K >> 6;
  for (int kt = 0; kt < NT - 1; ++kt) {
    const int Ab = (kt & 1) * 32768;
    const int Bb = Ab + 16384;
    const int Sa = ((kt & 1) ^ 1) * 32768;
    const int Sb = Sa + 16384;

    // p0: quadrant (m0,n0)
    VMW4(); BARR();
    STA_(Sa, 0, 0, kt + 1); STA_(Sa, 0, 1, kt + 1);
    STB_(Sb, 0, 0, kt + 1); STB_(Sb, 0, 1, kt + 1);
    LDA_(Ab, 0); LDB_(Bb, 0);
    MF_(0, 0);

    // p1: quadrant (m1,n0) — bfr (B half 0) held
    VMW4(); BARR();
    STA_(Sa, 1, 0, kt + 1); STA_(Sa, 1, 1, kt + 1);
    STB_(Sb, 1, 0, kt + 1); STB_(Sb, 1, 1, kt + 1);
    LDA_(Ab, 1);
    MF_(1, 0);

    // p2: quadrant (m1,n1) — free-running, reload bfr with B half 1
    LDB_(Bb, 1);
    MF_(1, 1);

    // p3: quadrant (m0,n1) — free-running, bfr held
    LDA_(Ab, 0);
    MF_(0, 1);
  }

  // peeled last tile
  {
    const int kt = NT - 1;
    const int Ab = (kt & 1) * 32768;
    const int Bb = Ab + 16384;
    VMW4(); BARR();
    LDA_(Ab, 0); LDB_(Bb, 0);
    MF_(0, 0);
    VMW0(); BARR();
    LDA_(Ab, 1);
    MF_(1, 0);
    LDB_(Bb, 1);
    MF_(1, 1);
    LDA_(Ab, 0);
    MF_(0, 1);
  }
#undef STA_
#undef STB_
#undef LDA_
#undef LDB_
#undef MF_
#undef VMW4
#undef VMW0
#undef BARR
}

// =====================================================================
// CORE B (r12-benched; r15/r19/r21 wall-clock-pinned best for pv):
// 256x128xK, BK=32, 8 waves (4x2), 6-buffer LDS ring (144 KB), DEPTH-4
// prefetch, counted vmcnt taper 12/9/6/3/0, stage-before-wait.
// =====================================================================
DEVINL void core256x128(const unsigned short* __restrict__ A, int lda,
                        const unsigned short* __restrict__ B, int ldb,
                        int K, int brow, int bcol, f32x4 acc[4][4])
{
  __shared__ unsigned short lds[73728];   // 144 KB = 6 x 12288 ushorts
  const int t = threadIdx.x;              // 0..511
  const int w = t >> 6, l = t & 63;
  const int wr = w >> 1, wc = w & 1;      // wave grid 4x2
  const int l15 = l & 15;
  const int scol = ((l & 3) ^ ((l >> 3) & 3)) << 3;        // staging source col
  const int cs   = (((l >> 4) ^ ((l15 >> 1) & 3)) << 3);   // read col

  const unsigned short* aL = A + (size_t)(brow * 256 + w * 16 + (l >> 2)) * lda + scol;
  const unsigned short* bL = B + (size_t)(bcol * 128 + w * 16 + (l >> 2)) * ldb + scol;

#pragma unroll
  for (int m = 0; m < 4; ++m)
#pragma unroll
    for (int n = 0; n < 4; ++n) {
      f32x4 z = {0.f, 0.f, 0.f, 0.f};
      acc[m][n] = z;
    }

#define STAGE(buf, kt)                                                         \
  {                                                                            \
    gll16(aL + (size_t)(kt) * 32,                                              \
          lds + (buf) * 12288 + w * 512);                                      \
    gll16(aL + (size_t)128 * lda + (size_t)(kt) * 32,                          \
          lds + (buf) * 12288 + 4096 + w * 512);                               \
    gll16(bL + (size_t)(kt) * 32,                                              \
          lds + (buf) * 12288 + 8192 + w * 512);                               \
  }

  const int NT = K >> 5;

  // prologue: stage tiles 0..3 into bufs 0..3 (12 loads in flight)
  STAGE(0, 0); STAGE(1, 1); STAGE(2, 2); STAGE(3, 3);

  bf16x8 af[4], bfv[4];
  int cur = 0;
  for (int kt = 0; kt < NT; ++kt) {
    int st = cur + 4; if (st >= 6) st -= 6;
    if (kt + 4 < NT) STAGE(st, kt + 4);

    const int rem = NT - 1 - kt;
    if (rem >= 4)      asm volatile("s_waitcnt vmcnt(12)" ::: "memory");
    else if (rem == 3) asm volatile("s_waitcnt vmcnt(9)"  ::: "memory");
    else if (rem == 2) asm volatile("s_waitcnt vmcnt(6)"  ::: "memory");
    else if (rem == 1) asm volatile("s_waitcnt vmcnt(3)"  ::: "memory");
    else               asm volatile("s_waitcnt vmcnt(0)"  ::: "memory");
    asm volatile("" ::: "memory");
    __builtin_amdgcn_s_barrier();
    asm volatile("" ::: "memory");

    const unsigned short* base = lds + cur * 12288;
#pragma unroll
    for (int m = 0; m < 4; ++m)
      af[m] = *(const bf16x8*)(base + (wr * 64 + m * 16 + l15) * 32 + cs);
#pragma unroll
    for (int n = 0; n < 4; ++n)
      bfv[n] = *(const bf16x8*)(base + 8192 + (wc * 64 + n * 16 + l15) * 32 + cs);

    __builtin_amdgcn_s_setprio(1);
#pragma unroll
    for (int m = 0; m < 4; ++m)
#pragma unroll
      for (int n = 0; n < 4; ++n)
        acc[m][n] = __builtin_amdgcn_mfma_f32_16x16x32_bf16(af[m], bfv[n], acc[m][n], 0, 0, 0);
    __builtin_amdgcn_s_setprio(0);

    cur = (cur + 1 == 6) ? 0 : cur + 1;
  }
#undef STAGE
}

// ---------- scores (CORE A): S = bf16( (A B^T) * scale ), [4096 x 4096] ----------
__global__ __launch_bounds__(512, 1)
void gemm256_scores(const unsigned short* __restrict__ A,
                    const unsigned short* __restrict__ B,
                    unsigned short* __restrict__ S, float scale)
{
  const B3 b = xcd_remap(16, 16, 1);
  f32x4 acc[8][4];
  core256v2(A, DIM, B, DIM, DIM, b.by, b.bx, acc);

  const int t = threadIdx.x, w = t >> 6, l = t & 63;
  const int wr = w >> 2, wc = w & 3;
  const int r4 = (l >> 4) * 4, c = l & 15;
  const int row0 = b.by * 256 + wr * 128;
  const int col0 = b.bx * 256 + wc * 64;
#pragma unroll
  for (int mf = 0; mf < 8; ++mf)
#pragma unroll
    for (int nf = 0; nf < 4; ++nf)
#pragma unroll
      for (int i = 0; i < 4; ++i)
        S[(size_t)(row0 + mf*16 + r4 + i) * NTOK + col0 + nf*16 + c] =
            f2bf(acc[mf][nf][i] * scale);
}

// ---------- merged QKV (CORE A): grid.z = 6; v outputs transposed ----------
__global__ __launch_bounds__(512, 1)
void qkv256(const unsigned short* __restrict__ x1, const unsigned short* __restrict__ x2,
            const unsigned short* __restrict__ W6,
            const float* bq1, const float* bk1, const float* bv1,
            const float* bq2, const float* bk2, const float* bv2,
            unsigned short* q1, unsigned short* k1, unsigned short* v1T,
            unsigned short* q2, unsigned short* k2, unsigned short* v2T)
{
  const B3 b = xcd_remap(4, 16, 6);
  const int g = b.bz;
  const unsigned short* A = (g < 3) ? x1 : x2;
  const unsigned short* W = W6 + (size_t)g * (DIM * DIM);
  const float* bias = (g == 0) ? bq1 : (g == 1) ? bk1 : (g == 2) ? bv1
                    : (g == 3) ? bq2 : (g == 4) ? bk2 : bv2;
  unsigned short* out = (g == 0) ? q1 : (g == 1) ? k1 : (g == 2) ? v1T
                      : (g == 3) ? q2 : (g == 4) ? k2 : v2T;
  const bool vT = (g == 2 || g == 5);

  f32x4 acc[8][4];
  core256v2(A, DIM, W, DIM, DIM, b.by, b.bx, acc);

  const int t = threadIdx.x, w = t >> 6, l = t & 63;
  const int wr = w >> 2, wc = w & 3;
  const int r4 = (l >> 4) * 4, c = l & 15;
  const int row0 = b.by * 256 + wr * 128;
  const int col0 = b.bx * 256 + wc * 64;

  float bias_v[4];
#pragma unroll
  for (int nf = 0; nf < 4; ++nf) bias_v[nf] = bias[col0 + nf*16 + c];

  if (!vT) {
#pragma unroll
    for (int mf = 0; mf < 8; ++mf)
#pragma unroll
      for (int nf = 0; nf < 4; ++nf)
#pragma unroll
        for (int i = 0; i < 4; ++i)
          out[(size_t)(row0 + mf*16 + r4 + i) * DIM + col0 + nf*16 + c] =
              f2bf(acc[mf][nf][i] + bias_v[nf]);
  } else {
#pragma unroll
    for (int mf = 0; mf < 8; ++mf)
#pragma unroll
      for (int nf = 0; nf < 4; ++nf) {
        short4v pk;
#pragma unroll
        for (int i = 0; i < 4; ++i) pk[i] = (short)f2bf(acc[mf][nf][i] + bias_v[nf]);
        *(short4v*)(out + (size_t)(col0 + nf*16 + c) * NTOK + row0 + mf*16 + r4) = pk;
      }
  }
}

// ---------- fused PV (CORE B, NO split-K): C[4096 x 2048] ----------
__global__ __launch_bounds__(512, 2)
void pv_gemm(const unsigned short* __restrict__ S1,
             const unsigned short* __restrict__ S2,
             const unsigned short* __restrict__ vTcat,
             float* __restrict__ out)
{
  const B3 b = xcd_remap(16, 16, 1);
  const int bx = b.bx, by = b.by;
  const unsigned short* A = (bx < 8) ? S1 : S2;

  f32x4 acc[4][4];
  core256x128(A, NTOK, vTcat, NTOK, NTOK, by, bx, acc);

  const int t = threadIdx.x, w = t >> 6, l = t & 63;
  const int wr = w >> 1, wc = w & 1;
  const int rr = (l >> 4) * 4, cc = l & 15;
#pragma unroll
  for (int m = 0; m < 4; ++m) {
    const int row0 = by * 256 + wr * 64 + m * 16 + rr;
#pragma unroll
    for (int n = 0; n < 4; ++n) {
      const int cg = bx * 128 + wc * 64 + n * 16 + cc;
      float* dstBase = (cg < 1024) ? (out + cg) : (out + 4194304 + (cg - 1024));
#pragma unroll
      for (int i = 0; i < 4; ++i)
        dstBase[(size_t)(row0 + i) * 1024] = acc[m][n][i];
    }
  }
}

// ---------- fused row softmax over contiguous S1||S2 (8192 rows) ----------
__global__ __launch_bounds__(256)
void softmax_inplace(unsigned short* __restrict__ S)
{
  const int row = blockIdx.x;
  unsigned short* r = S + (size_t)row * NTOK;
  const int t = threadIdx.x, wave = t >> 6, lane = t & 63;
  __shared__ float red[4];

  bf16x8 d0 = *(const bf16x8*)(r + t * 8);
  bf16x8 d1 = *(const bf16x8*)(r + 2048 + t * 8);
  float v[16];
  {
    const unsigned short* p0 = (const unsigned short*)&d0;
    const unsigned short* p1 = (const unsigned short*)&d1;
#pragma unroll
    for (int j = 0; j < 8; ++j) { v[j] = bf2f(p0[j]); v[8 + j] = bf2f(p1[j]); }
  }
  float mx = v[0];
#pragma unroll
  for (int j = 1; j < 16; ++j) mx = fmaxf(mx, v[j]);
#pragma unroll
  for (int o = 32; o > 0; o >>= 1) mx = fmaxf(mx, __shfl_xor(mx, o));
  if (lane == 0) red[wave] = mx;
  __syncthreads();
  mx = fmaxf(fmaxf(red[0], red[1]), fmaxf(red[2], red[3]));

  float s = 0.f;
#pragma unroll
  for (int j = 0; j < 16; ++j) { v[j] = __expf(v[j] - mx); s += v[j]; }
#pragma unroll
  for (int o = 32; o > 0; o >>= 1) s += __shfl_xor(s, o);
  __syncthreads();
  if (lane == 0) red[wave] = s;
  __syncthreads();
  s = red[0] + red[1] + red[2] + red[3];
  const float inv = 1.0f / s;

  unsigned short o0[8], o1[8];
#pragma unroll
  for (int j = 0; j < 8; ++j) { o0[j] = f2bf(v[j] * inv); o1[j] = f2bf(v[8 + j] * inv); }
  *(bf16x8*)(r + t * 8)        = *(const bf16x8*)o0;
  *(bf16x8*)(r + 2048 + t * 8) = *(const bf16x8*)o1;
}

// ---------- ONE fused fp32->bf16 converter for x1|x2|W6 (14M elems contiguous) ----------
// dst layout: [0,4M) x1b, [4M,8M) x2b, [8M,14M) W6 (6 x 1M weights).
// seg = elem_index >> 20 (all segment sizes are multiples of 1M elems).
__global__ __launch_bounds__(256)
void cvt_all(const float* x1, const float* x2,
             const float* w0, const float* w1, const float* w2,
             const float* w3, const float* w4, const float* w5,
             unsigned short* __restrict__ dst)
{
  const size_t i = ((size_t)blockIdx.x * 256 + threadIdx.x) * 4;
  const int seg = (int)(i >> 20);
  const float* src;
  size_t off;
  if (seg < 4)      { src = x1; off = i; }
  else if (seg < 8) { src = x2; off = i - (4u << 20); }
  else {
    const float* ws_[6] = {w0, w1, w2, w3, w4, w5};
    src = ws_[seg - 8];
    off = i - ((size_t)seg << 20);
  }
  float4v x = *(const float4v*)(src + off);
  short4v o;
#pragma unroll
  for (int j = 0; j < 4; ++j) o[j] = (short)f2bf(x[j]);
  *(short4v*)(dst + i) = o;
}

// ---------- host launcher ----------
extern "C" void kernel_launch(void* const* d_in, const int* in_sizes, int n_in,
                              void* d_out, int out_size, void* d_ws, size_t ws_size,
                              hipStream_t stream)
{
  const float* x1  = (const float*)d_in[0];
  const float* x2  = (const float*)d_in[1];
  const float* Wq1 = (const float*)d_in[2];  const float* bq1 = (const float*)d_in[3];
  const float* Wk1 = (const float*)d_in[4];  const float* bk1 = (const float*)d_in[5];
  const float* Wv1 = (const float*)d_in[6];  const float* bv1 = (const float*)d_in[7];
  const float* Wq2 = (const float*)d_in[8];  const float* bq2 = (const float*)d_in[9];
  const float* Wk2 = (const float*)d_in[10]; const float* bk2 = (const float*)d_in[11];
  const float* Wv2 = (const float*)d_in[12]; const float* bv2 = (const float*)d_in[13];
  float* out = (float*)d_out;

  // ws layout (ushort units):
  //  [0,16M):    x1b(4M) x2b(4M) W6(6M) pad -> later S1 [4096x4096]
  //  [16M,32M):  S2   (contiguous with S1 -> fused softmax over 8192 rows)
  //  [32M,48M):  q1 k1 q2 k2 (4M each)
  //  [48M,56M):  v1T v2T (vTcat, [2048 x 4096])
  unsigned short* ws  = (unsigned short*)d_ws;
  const size_t NTD = (size_t)NTOK * DIM;           // 4M elems
  const size_t SM  = (size_t)NTOK * NTOK;          // 16M elems
  unsigned short* x1b = ws;
  unsigned short* x2b = x1b + NTD;
  unsigned short* W6  = x2b + NTD;
  unsigned short* S1  = ws;
  unsigned short* S2  = ws + SM;
  unsigned short* q1  = ws + 2 * SM;
  unsigned short* k1  = q1 + NTD;
  unsigned short* q2  = k1 + NTD;
  unsigned short* k2  = q2 + NTD;
  unsigned short* vT  = k2 + NTD;                  // v1T followed by v2T
  unsigned short* v1T = vT;
  unsigned short* v2T = vT + NTD;

  const dim3 blk(256);

  // one fused conversion launch: x1b | x2b | W6 = 14M contiguous elems
  cvt_all<<<dim3((14u << 20) / 1024), blk, 0, stream>>>(
      x1, x2, Wq1, Wk1, Wv1, Wq2, Wk2, Wv2, ws);

  qkv256<<<dim3(4, 16, 6), dim3(512), 0, stream>>>(
      x1b, x2b, W6, bq1, bk1, bv1, bq2, bk2, bv2, q1, k1, v1T, q2, k2, v2T);

  const float scale = 0.03125f;  // 1/sqrt(1024)

  // two separate score launches (r15-verified remap / L2 behavior),
  // then ONE fused softmax over the contiguous S1||S2 region
  gemm256_scores<<<dim3(16, 16), dim3(512), 0, stream>>>(q2, k1, S1, scale);
  gemm256_scores<<<dim3(16, 16), dim3(512), 0, stream>>>(q1, k2, S2, scale);
  softmax_inplace<<<dim3(2 * NTOK), blk, 0, stream>>>(S1);

  // fused PV over [v1T; v2T], full K (no split, no partial add)
  pv_gemm<<<dim3(16, 16), dim3(512), 0, stream>>>(S1, S2, vT, out);
}